// Round 18
// baseline (205.709 us; speedup 1.0000x reference)
//
#include <hip/hip_runtime.h>
#include <hip/hip_bf16.h>
#include <cstdint>

#define D 128
#define RPB 256            // rows per bucket (8-bit in-bucket row)
#define RPB_SHIFT 8
#define NBMAX 512
#define P1CHUNK 8192       // edges per pass1 chunk
#define CAP 9216           // fixed bucket capacity: mean 8192, +11.3 sigma
#define OVFCAP 4096        // overflow list capacity (statistically unused)

using bf16x8 = __attribute__((ext_vector_type(8))) short;
using f32x4  = __attribute__((ext_vector_type(4))) float;
using f32x2  = __attribute__((ext_vector_type(2))) float;
using s16x8  = __attribute__((ext_vector_type(8))) short;

static __device__ inline unsigned short f2bf(float f) {
    __hip_bfloat16 b = __float2bfloat16(f);
    return reinterpret_cast<unsigned short&>(b);
}

#if defined(__has_builtin)
#if __has_builtin(__builtin_amdgcn_global_load_lds)
#define HAS_GLL 1
#endif
#endif

#ifdef HAS_GLL
// async 16B global->LDS. LDS dest is wave-uniform base + lane*16 (HW rule).
static __device__ __forceinline__ void gll16(const void* g, void* l) {
    __builtin_amdgcn_global_load_lds(
        (const __attribute__((address_space(1))) unsigned int*)(uintptr_t)g,
        (__attribute__((address_space(3))) unsigned int*)(uintptr_t)l,
        16, 0, 0);
}
#endif

// ---------------- precvt: x,W f32 -> bf16 (streaming, vectorized) -----------
__global__ __launch_bounds__(256) void precvt_kernel(
    const float* __restrict__ x, const float* __restrict__ W,
    unsigned short* __restrict__ xbf, unsigned short* __restrict__ wbf,
    long xc8, long wc8)
{
    long total = xc8 + wc8;
    for (long i = blockIdx.x * 256L + threadIdx.x; i < total;
         i += (long)gridDim.x * 256L) {
        const float* src; unsigned short* dst; long j;
        if (i < xc8) { src = x; dst = xbf; j = i; }
        else         { src = W; dst = wbf; j = i - xc8; }
        float4 a = *reinterpret_cast<const float4*>(src + j * 8);
        float4 b = *reinterpret_cast<const float4*>(src + j * 8 + 4);
        ushort4 lo = make_ushort4(f2bf(a.x), f2bf(a.y), f2bf(a.z), f2bf(a.w));
        ushort4 hi = make_ushort4(f2bf(b.x), f2bf(b.y), f2bf(b.z), f2bf(b.w));
        *reinterpret_cast<ushort4*>(dst + j * 8)     = lo;
        *reinterpret_cast<ushort4*>(dst + j * 8 + 4) = hi;
    }
}

// ---- fused (bf16 inputs): gemm 64-row tile + fixed-cap pass1, interleaved --
__global__ __launch_bounds__(256) void gemm_pass1_bf_kernel(
    const unsigned short* __restrict__ xbf, const unsigned short* __restrict__ wbf,
    const float* __restrict__ bias, __hip_bfloat16* __restrict__ h, int N,
    const int* __restrict__ rows, const int* __restrict__ cols,
    const float* __restrict__ vals,
    int* __restrict__ bcount, uint2* __restrict__ pairs, uint4* __restrict__ ovf,
    int NB, int E, int GB, int HB)
{
    __shared__ __align__(16) char smem[48 * 1024];
    const int tid = threadIdx.x;

    const int T   = GB + HB;
    const int bid = blockIdx.x;
    const int p_before = (int)(((long long)bid * HB) / T);
    const int p_after  = (int)(((long long)(bid + 1) * HB) / T);

    if (p_after > p_before) {
        // ---------- pass1 block (proven R14-R17) ----------
        int* srows = reinterpret_cast<int*>(smem);
        int* lh    = reinterpret_cast<int*>(smem + 32 * 1024);
        int* lbase = reinterpret_cast<int*>(smem + 34 * 1024);

        const int base = p_before * P1CHUNK;

        for (int i = tid; i < NBMAX; i += 256) lh[i] = 0;
        __syncthreads();

#pragma unroll 4
        for (int it = 0; it < P1CHUNK / 256; ++it) {
            int e = base + it * 256 + tid;
            int r = (e < E) ? rows[e] : -1;
            srows[it * 256 + tid] = r;
            if (r >= 0) atomicAdd(&lh[r >> RPB_SHIFT], 1);
        }
        __syncthreads();

        for (int i = tid; i < NBMAX; i += 256) {
            int c = lh[i];
            lbase[i] = c ? (i * CAP + atomicAdd(&bcount[i], c)) : 0;
            lh[i] = 0;
        }
        __syncthreads();

#pragma unroll 4
        for (int it = 0; it < P1CHUNK / 256; ++it) {
            int e = base + it * 256 + tid;
            int r = srows[it * 256 + tid];
            if (r < 0) continue;
            int b = r >> RPB_SHIFT;
            int lofs = atomicAdd(&lh[b], 1);
            int pos = lbase[b] + lofs;
            if (pos < (b + 1) * CAP) {
                unsigned packed = ((unsigned)(r & (RPB - 1)) << 17) | (unsigned)cols[e];
                pairs[pos] = make_uint2(packed, __float_as_uint(vals[e]));
            } else {
                int oi = atomicAdd(&bcount[NB], 1);
                if (oi < OVFCAP)
                    ovf[oi] = make_uint4((unsigned)r, (unsigned)cols[e],
                                         __float_as_uint(vals[e]), 0u);
            }
        }
        return;
    }

    // ---------- gemm block: 64x128 tile, bf16 inputs ----------
    const int gb = bid - p_before;
    char* sA = smem;                 // 64 x 128 bf16, swizzled (16 KB)
    char* sB = smem + 16 * 1024;     // 128 x 128 bf16, swizzled (32 KB)
    const int nbase = gb * 64;
    const int wid  = tid >> 6;
    const int lane = tid & 63;

#ifdef HAS_GLL
    if (nbase + 64 <= N) {
        // async staging: linear LDS dest + inverse-swizzled global source.
        // chunk k = 1024B = rows 4k..4k+3; lane l -> (row=4k+(l>>4), u=l&15);
        // source elem = row*128 + (u ^ (row&7))*8  (XOR is an involution).
        const int row_in = lane >> 4;
        const int u      = lane & 15;
#pragma unroll
        for (int i = 0; i < 8; ++i) {              // sB: 32 chunks, 8 per wave
            int k   = wid * 8 + i;
            int row = k * 4 + row_in;
            int su  = u ^ (row & 7);
            gll16(wbf + row * D + su * 8, sB + k * 1024);
        }
#pragma unroll
        for (int i = 0; i < 4; ++i) {              // sA: 16 chunks, 4 per wave
            int k   = wid * 4 + i;
            int row = k * 4 + row_in;
            int su  = u ^ (row & 7);
            gll16(xbf + (size_t)(nbase + row) * D + su * 8, sA + k * 1024);
        }
    } else
#endif
    {
        // manual bf16 restage (bounds-checked; also the no-builtin fallback)
#pragma unroll
        for (int i = 0; i < 8; ++i) {
            int g = i * 256 + tid;                 // 0..2047 16B-units of sB
            int row = g >> 4, u = g & 15;
            unsigned addr = (unsigned)(row * 256 + ((u ^ (row & 7)) << 4));
            *reinterpret_cast<s16x8*>(sB + addr) =
                *reinterpret_cast<const s16x8*>(wbf + row * D + u * 8);
        }
#pragma unroll
        for (int i = 0; i < 4; ++i) {
            int g = i * 256 + tid;                 // 0..1023 16B-units of sA
            int row = g >> 4, u = g & 15;
            unsigned addr = (unsigned)(row * 256 + ((u ^ (row & 7)) << 4));
            int gr = nbase + row;
            s16x8 v = {};
            if (gr < N)
                v = *reinterpret_cast<const s16x8*>(xbf + (size_t)gr * D + u * 8);
            *reinterpret_cast<s16x8*>(sA + addr) = v;
        }
    }
    __syncthreads();

    const int wr   = (wid >> 1) * 32;
    const int wc   = (wid & 1) * 64;
    const int lrow = lane & 15;
    const int lkb  = (lane >> 4) * 16;

    f32x4 acc[2][4] = {};

#pragma unroll
    for (int kk = 0; kk < 4; ++kk) {
        const int kbyte = kk * 64 + lkb;
        bf16x8 a[2], b[4];
#pragma unroll
        for (int m = 0; m < 2; ++m) {
            const int row = wr + m * 16 + lrow;
            const unsigned addr = (unsigned)((row * 256 + kbyte) ^ ((row & 7) << 4));
            a[m] = *reinterpret_cast<const bf16x8*>(sA + addr);
        }
#pragma unroll
        for (int n = 0; n < 4; ++n) {
            const int row = wc + n * 16 + lrow;
            const unsigned addr = (unsigned)((row * 256 + kbyte) ^ ((row & 7) << 4));
            b[n] = *reinterpret_cast<const bf16x8*>(sB + addr);
        }
#pragma unroll
        for (int m = 0; m < 2; ++m)
#pragma unroll
            for (int n = 0; n < 4; ++n)
                acc[m][n] = __builtin_amdgcn_mfma_f32_16x16x32_bf16(a[m], b[n], acc[m][n], 0, 0, 0);
    }

    float bv[4];
#pragma unroll
    for (int n = 0; n < 4; ++n) bv[n] = bias[wc + n * 16 + lrow];

#pragma unroll
    for (int m = 0; m < 2; ++m) {
        const int row0 = nbase + wr + m * 16 + (lane >> 4) * 4;
#pragma unroll
        for (int n = 0; n < 4; ++n) {
            const int col = wc + n * 16 + lrow;
#pragma unroll
            for (int r = 0; r < 4; ++r) {
                const int grow = row0 + r;
                if (grow < N)
                    h[(size_t)grow * D + col] = __float2bfloat16(acc[m][n][r] + bv[n]);
            }
        }
    }
}

// ---- fused (f32 inputs, R17 proven) — mid-ladder fallback ------------------
__global__ __launch_bounds__(256) void gemm_pass1_kernel(
    const float* __restrict__ x, const float* __restrict__ W,
    const float* __restrict__ bias, __hip_bfloat16* __restrict__ h, int N,
    const int* __restrict__ rows, const int* __restrict__ cols,
    const float* __restrict__ vals,
    int* __restrict__ bcount, uint2* __restrict__ pairs, uint4* __restrict__ ovf,
    int NB, int E, int GB, int HB)
{
    __shared__ __align__(16) char smem[48 * 1024];
    const int tid = threadIdx.x;

    const int T   = GB + HB;
    const int bid = blockIdx.x;
    const int p_before = (int)(((long long)bid * HB) / T);
    const int p_after  = (int)(((long long)(bid + 1) * HB) / T);

    if (p_after > p_before) {
        int* srows = reinterpret_cast<int*>(smem);
        int* lh    = reinterpret_cast<int*>(smem + 32 * 1024);
        int* lbase = reinterpret_cast<int*>(smem + 34 * 1024);

        const int base = p_before * P1CHUNK;

        for (int i = tid; i < NBMAX; i += 256) lh[i] = 0;
        __syncthreads();

#pragma unroll 4
        for (int it = 0; it < P1CHUNK / 256; ++it) {
            int e = base + it * 256 + tid;
            int r = (e < E) ? rows[e] : -1;
            srows[it * 256 + tid] = r;
            if (r >= 0) atomicAdd(&lh[r >> RPB_SHIFT], 1);
        }
        __syncthreads();

        for (int i = tid; i < NBMAX; i += 256) {
            int c = lh[i];
            lbase[i] = c ? (i * CAP + atomicAdd(&bcount[i], c)) : 0;
            lh[i] = 0;
        }
        __syncthreads();

#pragma unroll 4
        for (int it = 0; it < P1CHUNK / 256; ++it) {
            int e = base + it * 256 + tid;
            int r = srows[it * 256 + tid];
            if (r < 0) continue;
            int b = r >> RPB_SHIFT;
            int lofs = atomicAdd(&lh[b], 1);
            int pos = lbase[b] + lofs;
            if (pos < (b + 1) * CAP) {
                unsigned packed = ((unsigned)(r & (RPB - 1)) << 17) | (unsigned)cols[e];
                pairs[pos] = make_uint2(packed, __float_as_uint(vals[e]));
            } else {
                int oi = atomicAdd(&bcount[NB], 1);
                if (oi < OVFCAP)
                    ovf[oi] = make_uint4((unsigned)r, (unsigned)cols[e],
                                         __float_as_uint(vals[e]), 0u);
            }
        }
        return;
    }

    const int gb = bid - p_before;
    char* sA = smem;
    char* sB = smem + 16 * 1024;
    const int nbase = gb * 64;

#pragma unroll
    for (int it = 0; it < 16; ++it) {
        const int r = it * 8 + (tid >> 5);
        const int c = (tid & 31) * 4;
        const unsigned addr = (unsigned)((r * 256 + c * 2) ^ ((r & 7) << 4));

        float4 wv = *reinterpret_cast<const float4*>(W + (size_t)r * D + c);
        ushort4 wb = make_ushort4(f2bf(wv.x), f2bf(wv.y), f2bf(wv.z), f2bf(wv.w));
        *reinterpret_cast<ushort4*>(sB + addr) = wb;

        if (it < 8) {
            const int gr = nbase + r;
            float4 xv = make_float4(0.f, 0.f, 0.f, 0.f);
            if (gr < N) xv = *reinterpret_cast<const float4*>(x + (size_t)gr * D + c);
            ushort4 xb = make_ushort4(f2bf(xv.x), f2bf(xv.y), f2bf(xv.z), f2bf(xv.w));
            *reinterpret_cast<ushort4*>(sA + addr) = xb;
        }
    }
    __syncthreads();

    const int wid  = tid >> 6;
    const int lane = tid & 63;
    const int wr   = (wid >> 1) * 32;
    const int wc   = (wid & 1) * 64;
    const int lrow = lane & 15;
    const int lkb  = (lane >> 4) * 16;

    f32x4 acc[2][4] = {};

#pragma unroll
    for (int kk = 0; kk < 4; ++kk) {
        const int kbyte = kk * 64 + lkb;
        bf16x8 a[2], b[4];
#pragma unroll
        for (int m = 0; m < 2; ++m) {
            const int row = wr + m * 16 + lrow;
            const unsigned addr = (unsigned)((row * 256 + kbyte) ^ ((row & 7) << 4));
            a[m] = *reinterpret_cast<const bf16x8*>(sA + addr);
        }
#pragma unroll
        for (int n = 0; n < 4; ++n) {
            const int row = wc + n * 16 + lrow;
            const unsigned addr = (unsigned)((row * 256 + kbyte) ^ ((row & 7) << 4));
            b[n] = *reinterpret_cast<const bf16x8*>(sB + addr);
        }
#pragma unroll
        for (int m = 0; m < 2; ++m)
#pragma unroll
            for (int n = 0; n < 4; ++n)
                acc[m][n] = __builtin_amdgcn_mfma_f32_16x16x32_bf16(a[m], b[n], acc[m][n], 0, 0, 0);
    }

    float bv[4];
#pragma unroll
    for (int n = 0; n < 4; ++n) bv[n] = bias[wc + n * 16 + lrow];

#pragma unroll
    for (int m = 0; m < 2; ++m) {
        const int row0 = nbase + wr + m * 16 + (lane >> 4) * 4;
#pragma unroll
        for (int n = 0; n < 4; ++n) {
            const int col = wc + n * 16 + lrow;
#pragma unroll
            for (int r = 0; r < 4; ++r) {
                const int grow = row0 + r;
                if (grow < N)
                    h[(size_t)grow * D + col] = __float2bfloat16(acc[m][n][r] + bv[n]);
            }
        }
    }
}

// ---- pass2: sort bucket [b*CAP, b*CAP+cnt) in place + row start/end --------
__global__ __launch_bounds__(256) void pass2_fixed_kernel(
    uint2* __restrict__ pairs, const int* __restrict__ bcount,
    int* __restrict__ rowstart, int* __restrict__ rowend, int N)
{
    __shared__ uint2 st[CAP];
    __shared__ int rh[RPB];
    __shared__ int sc[RPB];
    __shared__ int cur[RPB];

    const int b   = blockIdx.x;
    const int tid = threadIdx.x;
    const int start = b * CAP;
    int cnt = bcount[b];
    if (cnt > CAP) cnt = CAP;

    rh[tid] = 0;
    __syncthreads();

    for (int i = tid; i < cnt; i += 256) {
        uint2 p = pairs[start + i];
        st[i] = p;
        atomicAdd(&rh[p.x >> 17], 1);
    }
    __syncthreads();

    int myc = rh[tid];
    sc[tid] = myc;
    __syncthreads();
    for (int off = 1; off < 256; off <<= 1) {
        int t = (tid >= off) ? sc[tid - off] : 0;
        __syncthreads();
        sc[tid] += t;
        __syncthreads();
    }
    int excl = sc[tid] - myc;
    cur[tid] = start + excl;
    int grow = b * RPB + tid;
    if (grow < N) {
        rowstart[grow] = start + excl;
        rowend[grow]   = start + excl + myc;
    }
    __syncthreads();

    for (int i = tid; i < cnt; i += 256) {
        uint2 p = st[i];
        int r = (int)(p.x >> 17);
        int pos = atomicAdd(&cur[r], 1);
        pairs[pos] = make_uint2(p.x & 0x1FFFFu, p.y);
    }
}

// ---- row gather: rowstart/rowend; readlane broadcast (proven R11) ----------
__global__ __launch_bounds__(256) void row_gather2_kernel(
    const __hip_bfloat16* __restrict__ hbf, const uint2* __restrict__ pairs,
    const int* __restrict__ rowstart, const int* __restrict__ rowend,
    float* __restrict__ out, int N)
{
    int row  = (int)((blockIdx.x * (size_t)blockDim.x + threadIdx.x) >> 6);
    int lane = threadIdx.x & 63;
    if (row >= N) return;

    int start = rowstart[row];
    int end   = rowend[row];

    const char* hb = reinterpret_cast<const char*>(hbf);
    const unsigned lbyte = (unsigned)lane << 2;
    float ax = 0.f, ay = 0.f;

    for (int e0 = start; e0 < end; e0 += 64) {
        int pl = e0 + lane;
        if (pl >= end) pl = end - 1;
        uint2 p = pairs[pl];
        int pc = (int)p.x, pv = (int)p.y;
        int m = end - e0; if (m > 64) m = 64;

        int idx = 0;
        const int m16 = m & ~15;
        for (; idx < m16; idx += 16) {
            unsigned c[16], vb[16], hv[16];
#pragma unroll
            for (int u = 0; u < 16; ++u) {
                c[u]  = (unsigned)__builtin_amdgcn_readlane(pc, idx + u);
                vb[u] = (unsigned)__builtin_amdgcn_readlane(pv, idx + u);
            }
#pragma unroll
            for (int u = 0; u < 16; ++u)
                hv[u] = *reinterpret_cast<const unsigned*>(hb + (((size_t)c[u]) << 8) + lbyte);
#pragma unroll
            for (int u = 0; u < 16; ++u) {
                float v = __uint_as_float(vb[u]);
                ax += v * __uint_as_float(hv[u] << 16);
                ay += v * __uint_as_float(hv[u] & 0xffff0000u);
            }
        }
        const int m8 = m & ~7;
        for (; idx < m8; idx += 8) {
            unsigned c[8], vb[8], hv[8];
#pragma unroll
            for (int u = 0; u < 8; ++u) {
                c[u]  = (unsigned)__builtin_amdgcn_readlane(pc, idx + u);
                vb[u] = (unsigned)__builtin_amdgcn_readlane(pv, idx + u);
            }
#pragma unroll
            for (int u = 0; u < 8; ++u)
                hv[u] = *reinterpret_cast<const unsigned*>(hb + (((size_t)c[u]) << 8) + lbyte);
#pragma unroll
            for (int u = 0; u < 8; ++u) {
                float v = __uint_as_float(vb[u]);
                ax += v * __uint_as_float(hv[u] << 16);
                ay += v * __uint_as_float(hv[u] & 0xffff0000u);
            }
        }
        for (; idx < m; ++idx) {
            unsigned c  = (unsigned)__builtin_amdgcn_readlane(pc, idx);
            unsigned vb = (unsigned)__builtin_amdgcn_readlane(pv, idx);
            unsigned hv = *reinterpret_cast<const unsigned*>(hb + (((size_t)c) << 8) + lbyte);
            float v = __uint_as_float(vb);
            ax += v * __uint_as_float(hv << 16);
            ay += v * __uint_as_float(hv & 0xffff0000u);
        }
    }

    f32x2 r2 = { ax, ay };
    __builtin_nontemporal_store(r2, reinterpret_cast<f32x2*>(out + (size_t)row * D) + lane);
}

// ---- fixup: apply overflow edges (normally zero) via atomics ---------------
__global__ __launch_bounds__(256) void fixup_kernel(
    const uint4* __restrict__ ovf, const int* __restrict__ ovfcnt,
    const __hip_bfloat16* __restrict__ hbf, float* __restrict__ out, int N)
{
    int cnt = *ovfcnt;
    if (cnt > OVFCAP) cnt = OVFCAP;
    const int wid  = threadIdx.x >> 6;
    const int lane = threadIdx.x & 63;
    const unsigned short* hb = reinterpret_cast<const unsigned short*>(hbf);
    for (int i = wid; i < cnt; i += 4) {
        uint4 e = ovf[i];
        if ((int)e.x >= N) continue;
        unsigned hv = *reinterpret_cast<const unsigned*>(hb + (size_t)e.y * D + lane * 2);
        float v = __uint_as_float(e.z);
        atomicAdd(out + (size_t)e.x * D + lane * 2,     v * __uint_as_float(hv << 16));
        atomicAdd(out + (size_t)e.x * D + lane * 2 + 1, v * __uint_as_float(hv & 0xffff0000u));
    }
}

// ============ R1 fallback ============

__global__ __launch_bounds__(256) void gemm_kernel(
    const float* __restrict__ x, const float* __restrict__ W,
    const float* __restrict__ bias, float* __restrict__ h, int N)
{
    __shared__ float sWt[D][D];
    __shared__ float sx[16][D];
    const int tid = threadIdx.x;
    for (int idx = tid; idx < D * D; idx += 256) {
        int o = idx >> 7, i = idx & (D - 1);
        sWt[i][o] = W[idx];
    }
    const int nbase = blockIdx.x * 16;
    for (int idx = tid; idx < 16 * D; idx += 256) {
        int r = idx >> 7, i = idx & (D - 1);
        int n = nbase + r;
        sx[r][i] = (n < N) ? x[(size_t)n * D + i] : 0.0f;
    }
    __syncthreads();
    const int c = tid & (D - 1);
    const int rg = tid >> 7;
    float acc[8];
#pragma unroll
    for (int k = 0; k < 8; ++k) acc[k] = 0.0f;
#pragma unroll 4
    for (int i = 0; i < D; ++i) {
        float w = sWt[i][c];
#pragma unroll
        for (int k = 0; k < 8; ++k) acc[k] += sx[rg * 8 + k][i] * w;
    }
    const float b = bias[c];
#pragma unroll
    for (int k = 0; k < 8; ++k) {
        int n = nbase + rg * 8 + k;
        if (n < N) h[(size_t)n * D + c] = acc[k] + b;
    }
}

__global__ __launch_bounds__(256) void scatter_kernel(
    const float* __restrict__ h, const float* __restrict__ vals,
    const int* __restrict__ rows, const int* __restrict__ cols,
    float* __restrict__ out, int E)
{
    const int wid  = (int)((blockIdx.x * (size_t)blockDim.x + threadIdx.x) >> 6);
    const int lane = threadIdx.x & 63;
    if (wid >= E) return;
    const int   r = rows[wid];
    const int   c = cols[wid];
    const float v = vals[wid];
    float2 hv = *reinterpret_cast<const float2*>(h + (size_t)c * D + lane * 2);
    atomicAdd(out + (size_t)r * D + lane * 2,     v * hv.x);
    atomicAdd(out + (size_t)r * D + lane * 2 + 1, v * hv.y);
}

// ---------------- launch ----------------
static inline size_t align16(size_t x) { return (x + 15) & ~(size_t)15; }

extern "C" void kernel_launch(void* const* d_in, const int* in_sizes, int n_in,
                              void* d_out, int out_size, void* d_ws, size_t ws_size,
                              hipStream_t stream)
{
    const float* x    = (const float*)d_in[0];
    const float* W    = (const float*)d_in[1];
    const float* bias = (const float*)d_in[2];
    const float* vals = (const float*)d_in[3];
    const int*   rows = (const int*)d_in[4];
    const int*   cols = (const int*)d_in[5];

    const int N = in_sizes[0] / D;
    const int E = in_sizes[3];
    float* out = (float*)d_out;

    const int NB = (N + RPB - 1) / RPB;
    const int GB = (N + 63) / 64;
    const int HB = (E + P1CHUNK - 1) / P1CHUNK;

    // ---- tier-1 layout (bf16 pre-converted inputs) ----
    size_t t1_xbf    = 0;
    size_t t1_wbf    = t1_xbf    + align16((size_t)N * D * 2);
    size_t t1_h      = t1_wbf    + align16((size_t)D * D * 2);
    size_t t1_pairs  = t1_h      + align16((size_t)N * D * 2);
    size_t t1_rs     = t1_pairs  + align16((size_t)NB * CAP * 8);
    size_t t1_re     = t1_rs     + align16((size_t)N * 4);
    size_t t1_bcount = t1_re     + align16((size_t)N * 4);
    size_t t1_ovf    = t1_bcount + align16((size_t)(NB + 1) * 4);
    size_t need_t1   = t1_ovf    + align16((size_t)OVFCAP * 16);

    // ---- tier-2 layout (R17 proven, f32 inputs) ----
    size_t t2_h      = 0;
    size_t t2_pairs  = t2_h      + align16((size_t)N * D * 2);
    size_t t2_rs     = t2_pairs  + align16((size_t)NB * CAP * 8);
    size_t t2_re     = t2_rs     + align16((size_t)N * 4);
    size_t t2_bcount = t2_re     + align16((size_t)N * 4);
    size_t t2_ovf    = t2_bcount + align16((size_t)(NB + 1) * 4);
    size_t need_t2   = t2_ovf    + align16((size_t)OVFCAP * 16);

    if (ws_size >= need_t1 && NB <= NBMAX && N <= (1 << 17) && (N * D) % 8 == 0) {
        char* ws = (char*)d_ws;
        unsigned short* xbf = (unsigned short*)(ws + t1_xbf);
        unsigned short* wbf = (unsigned short*)(ws + t1_wbf);
        __hip_bfloat16* hbf = (__hip_bfloat16*)(ws + t1_h);
        uint2* pairs        = (uint2*)(ws + t1_pairs);
        int*   rowstart     = (int*)(ws + t1_rs);
        int*   rowend       = (int*)(ws + t1_re);
        int*   bcount       = (int*)(ws + t1_bcount);
        uint4* ovf          = (uint4*)(ws + t1_ovf);

        hipMemsetAsync(bcount, 0, (size_t)(NB + 1) * 4, stream);

        long xc8 = (long)N * D / 8;
        long wc8 = (long)D * D / 8;
        precvt_kernel<<<2048, 256, 0, stream>>>(x, W, xbf, wbf, xc8, wc8);

        gemm_pass1_bf_kernel<<<GB + HB, 256, 0, stream>>>(
            xbf, wbf, bias, hbf, N, rows, cols, vals,
            bcount, pairs, ovf, NB, E, GB, HB);

        pass2_fixed_kernel<<<NB, 256, 0, stream>>>(pairs, bcount, rowstart, rowend, N);

        int gblocks = (int)(((size_t)N * 64 + 255) / 256);
        row_gather2_kernel<<<gblocks, 256, 0, stream>>>(hbf, pairs, rowstart, rowend, out, N);

        fixup_kernel<<<1, 256, 0, stream>>>(ovf, bcount + NB, hbf, out, N);
    } else if (ws_size >= need_t2 && NB <= NBMAX && N <= (1 << 17)) {
        char* ws = (char*)d_ws;
        __hip_bfloat16* hbf = (__hip_bfloat16*)(ws + t2_h);
        uint2* pairs        = (uint2*)(ws + t2_pairs);
        int*   rowstart     = (int*)(ws + t2_rs);
        int*   rowend       = (int*)(ws + t2_re);
        int*   bcount       = (int*)(ws + t2_bcount);
        uint4* ovf          = (uint4*)(ws + t2_ovf);

        hipMemsetAsync(bcount, 0, (size_t)(NB + 1) * 4, stream);

        gemm_pass1_kernel<<<GB + HB, 256, 0, stream>>>(
            x, W, bias, hbf, N, rows, cols, vals, bcount, pairs, ovf, NB, E, GB, HB);

        pass2_fixed_kernel<<<NB, 256, 0, stream>>>(pairs, bcount, rowstart, rowend, N);

        int gblocks = (int)(((size_t)N * 64 + 255) / 256);
        row_gather2_kernel<<<gblocks, 256, 0, stream>>>(hbf, pairs, rowstart, rowend, out, N);

        fixup_kernel<<<1, 256, 0, stream>>>(ovf, bcount + NB, hbf, out, N);
    } else {
        float* h = (float*)d_ws;
        hipMemsetAsync(out, 0, (size_t)out_size * sizeof(float), stream);
        gemm_kernel<<<(N + 15) / 16, 256, 0, stream>>>(x, W, bias, h, N);
        scatter_kernel<<<(E + 3) / 4, 256, 0, stream>>>(h, vals, rows, cols, out, E);
    }
}

// Round 19
// 200.348 us; speedup vs baseline: 1.0268x; 1.0268x over previous
//
#include <hip/hip_runtime.h>
#include <hip/hip_bf16.h>
#include <cstdint>

#define D 128
#define RPB 256            // rows per bucket (8-bit in-bucket row)
#define RPB_SHIFT 8
#define NBMAX 512
#define P1CHUNK 8192       // edges per pass1 chunk
#define CAP 9216           // fixed bucket capacity: mean 8192, +11.3 sigma
#define OVFCAP 4096        // overflow list capacity (statistically unused)

using bf16x8 = __attribute__((ext_vector_type(8))) short;
using f32x4  = __attribute__((ext_vector_type(4))) float;
using f32x2  = __attribute__((ext_vector_type(2))) float;
using s16x8  = __attribute__((ext_vector_type(8))) short;

static __device__ inline unsigned short f2bf(float f) {
    __hip_bfloat16 b = __float2bfloat16(f);
    return reinterpret_cast<unsigned short&>(b);
}

#if defined(__has_builtin)
#if __has_builtin(__builtin_amdgcn_global_load_lds)
#define HAS_GLL 1
#endif
#endif

#ifdef HAS_GLL
// async 16B global->LDS. LDS dest is wave-uniform base + lane*16 (HW rule).
static __device__ __forceinline__ void gll16(const void* g, void* l) {
    __builtin_amdgcn_global_load_lds(
        (const __attribute__((address_space(1))) unsigned int*)(uintptr_t)g,
        (__attribute__((address_space(3))) unsigned int*)(uintptr_t)l,
        16, 0, 0);
}
#endif

// ---------------- wcvt: W f32 -> bf16 once (16K elems, ~1 us) ---------------
__global__ __launch_bounds__(256) void wcvt_kernel(
    const float* __restrict__ W, unsigned short* __restrict__ wbf)
{
    int i = blockIdx.x * 256 + threadIdx.x;    // 2048 threads x 8 elems
    float4 a = *reinterpret_cast<const float4*>(W + (size_t)i * 8);
    float4 b = *reinterpret_cast<const float4*>(W + (size_t)i * 8 + 4);
    ushort4 lo = make_ushort4(f2bf(a.x), f2bf(a.y), f2bf(a.z), f2bf(a.w));
    ushort4 hi = make_ushort4(f2bf(b.x), f2bf(b.y), f2bf(b.z), f2bf(b.w));
    *reinterpret_cast<ushort4*>(wbf + (size_t)i * 8)     = lo;
    *reinterpret_cast<ushort4*>(wbf + (size_t)i * 8 + 4) = hi;
}

// ---- fused: gemm 64-row tile (sB async from wbf, sA inline f32->bf16)
//      + fixed-cap pass1, Bresenham-interleaved ------------------------------
__global__ __launch_bounds__(256) void gemm_pass1_kernel(
    const float* __restrict__ x, const unsigned short* __restrict__ wbf,
    const float* __restrict__ bias, __hip_bfloat16* __restrict__ h, int N,
    const int* __restrict__ rows, const int* __restrict__ cols,
    const float* __restrict__ vals,
    int* __restrict__ bcount, uint2* __restrict__ pairs, uint4* __restrict__ ovf,
    int NB, int E, int GB, int HB)
{
    __shared__ __align__(16) char smem[48 * 1024];
    const int tid = threadIdx.x;

    const int T   = GB + HB;
    const int bid = blockIdx.x;
    const int p_before = (int)(((long long)bid * HB) / T);
    const int p_after  = (int)(((long long)(bid + 1) * HB) / T);

    if (p_after > p_before) {
        // ---------- pass1 block (proven R14-R18) ----------
        int* srows = reinterpret_cast<int*>(smem);                 // 32 KB
        int* lh    = reinterpret_cast<int*>(smem + 32 * 1024);     // 2 KB
        int* lbase = reinterpret_cast<int*>(smem + 34 * 1024);     // 2 KB

        const int base = p_before * P1CHUNK;

        for (int i = tid; i < NBMAX; i += 256) lh[i] = 0;
        __syncthreads();

#pragma unroll 4
        for (int it = 0; it < P1CHUNK / 256; ++it) {
            int e = base + it * 256 + tid;
            int r = (e < E) ? rows[e] : -1;
            srows[it * 256 + tid] = r;
            if (r >= 0) atomicAdd(&lh[r >> RPB_SHIFT], 1);
        }
        __syncthreads();

        for (int i = tid; i < NBMAX; i += 256) {
            int c = lh[i];
            lbase[i] = c ? (i * CAP + atomicAdd(&bcount[i], c)) : 0;
            lh[i] = 0;
        }
        __syncthreads();

#pragma unroll 4
        for (int it = 0; it < P1CHUNK / 256; ++it) {
            int e = base + it * 256 + tid;
            int r = srows[it * 256 + tid];
            if (r < 0) continue;
            int b = r >> RPB_SHIFT;
            int lofs = atomicAdd(&lh[b], 1);
            int pos = lbase[b] + lofs;
            if (pos < (b + 1) * CAP) {
                unsigned packed = ((unsigned)(r & (RPB - 1)) << 17) | (unsigned)cols[e];
                pairs[pos] = make_uint2(packed, __float_as_uint(vals[e]));
            } else {
                int oi = atomicAdd(&bcount[NB], 1);
                if (oi < OVFCAP)
                    ovf[oi] = make_uint4((unsigned)r, (unsigned)cols[e],
                                         __float_as_uint(vals[e]), 0u);
            }
        }
        return;
    }

    // ---------- gemm block: 64x128 tile ----------
    const int gb = bid - p_before;
    char* sA = smem;                 // 64 x 128 bf16, swizzled (16 KB)
    char* sB = smem + 16 * 1024;     // 128 x 128 bf16, swizzled (32 KB)
    const int nbase = gb * 64;
    const int wid  = tid >> 6;
    const int lane = tid & 63;

#ifdef HAS_GLL
    {
        // sB async: linear LDS dest + inverse-swizzled global source (m173).
        // chunk k = 1024B = rows 4k..4k+3; lane l -> (row=4k+(l>>4), u=l&15);
        // source elem = row*128 + (u ^ (row&7))*8  (XOR is an involution).
        const int row_in = lane >> 4;
        const int u      = lane & 15;
#pragma unroll
        for (int i = 0; i < 8; ++i) {              // 32 chunks, 8 per wave
            int k   = wid * 8 + i;
            int row = k * 4 + row_in;
            int su  = u ^ (row & 7);
            gll16(wbf + row * D + su * 8, sB + k * 1024);
        }
    }
#else
    {
        // manual sB restage from wbf (no-builtin fallback)
#pragma unroll
        for (int i = 0; i < 8; ++i) {
            int g = i * 256 + tid;                 // 0..2047 16B-units
            int row = g >> 4, u = g & 15;
            unsigned addr = (unsigned)(row * 256 + ((u ^ (row & 7)) << 4));
            *reinterpret_cast<s16x8*>(sB + addr) =
                *reinterpret_cast<const s16x8*>(wbf + row * D + u * 8);
        }
    }
#endif

    // sA inline: x is single-use, convert f32->bf16 during staging (R17 proven)
#pragma unroll
    for (int it = 0; it < 8; ++it) {
        const int r = it * 8 + (tid >> 5);
        const int c = (tid & 31) * 4;
        const unsigned addr = (unsigned)((r * 256 + c * 2) ^ ((r & 7) << 4));
        const int gr = nbase + r;
        float4 xv = make_float4(0.f, 0.f, 0.f, 0.f);
        if (gr < N) xv = *reinterpret_cast<const float4*>(x + (size_t)gr * D + c);
        ushort4 xb = make_ushort4(f2bf(xv.x), f2bf(xv.y), f2bf(xv.z), f2bf(xv.w));
        *reinterpret_cast<ushort4*>(sA + addr) = xb;
    }
    __syncthreads();

    const int wr   = (wid >> 1) * 32;
    const int wc   = (wid & 1) * 64;
    const int lrow = lane & 15;
    const int lkb  = (lane >> 4) * 16;

    f32x4 acc[2][4] = {};

#pragma unroll
    for (int kk = 0; kk < 4; ++kk) {
        const int kbyte = kk * 64 + lkb;
        bf16x8 a[2], b[4];
#pragma unroll
        for (int m = 0; m < 2; ++m) {
            const int row = wr + m * 16 + lrow;
            const unsigned addr = (unsigned)((row * 256 + kbyte) ^ ((row & 7) << 4));
            a[m] = *reinterpret_cast<const bf16x8*>(sA + addr);
        }
#pragma unroll
        for (int n = 0; n < 4; ++n) {
            const int row = wc + n * 16 + lrow;
            const unsigned addr = (unsigned)((row * 256 + kbyte) ^ ((row & 7) << 4));
            b[n] = *reinterpret_cast<const bf16x8*>(sB + addr);
        }
#pragma unroll
        for (int m = 0; m < 2; ++m)
#pragma unroll
            for (int n = 0; n < 4; ++n)
                acc[m][n] = __builtin_amdgcn_mfma_f32_16x16x32_bf16(a[m], b[n], acc[m][n], 0, 0, 0);
    }

    float bv[4];
#pragma unroll
    for (int n = 0; n < 4; ++n) bv[n] = bias[wc + n * 16 + lrow];

#pragma unroll
    for (int m = 0; m < 2; ++m) {
        const int row0 = nbase + wr + m * 16 + (lane >> 4) * 4;
#pragma unroll
        for (int n = 0; n < 4; ++n) {
            const int col = wc + n * 16 + lrow;
#pragma unroll
            for (int r = 0; r < 4; ++r) {
                const int grow = row0 + r;
                if (grow < N)
                    h[(size_t)grow * D + col] = __float2bfloat16(acc[m][n][r] + bv[n]);
            }
        }
    }
}

// ---- pass2: sort bucket [b*CAP, b*CAP+cnt) in place + row start/end --------
__global__ __launch_bounds__(256) void pass2_fixed_kernel(
    uint2* __restrict__ pairs, const int* __restrict__ bcount,
    int* __restrict__ rowstart, int* __restrict__ rowend, int N)
{
    __shared__ uint2 st[CAP];
    __shared__ int rh[RPB];
    __shared__ int sc[RPB];
    __shared__ int cur[RPB];

    const int b   = blockIdx.x;
    const int tid = threadIdx.x;
    const int start = b * CAP;
    int cnt = bcount[b];
    if (cnt > CAP) cnt = CAP;

    rh[tid] = 0;
    __syncthreads();

    for (int i = tid; i < cnt; i += 256) {
        uint2 p = pairs[start + i];
        st[i] = p;
        atomicAdd(&rh[p.x >> 17], 1);
    }
    __syncthreads();

    int myc = rh[tid];
    sc[tid] = myc;
    __syncthreads();
    for (int off = 1; off < 256; off <<= 1) {
        int t = (tid >= off) ? sc[tid - off] : 0;
        __syncthreads();
        sc[tid] += t;
        __syncthreads();
    }
    int excl = sc[tid] - myc;
    cur[tid] = start + excl;
    int grow = b * RPB + tid;
    if (grow < N) {
        rowstart[grow] = start + excl;
        rowend[grow]   = start + excl + myc;
    }
    __syncthreads();

    for (int i = tid; i < cnt; i += 256) {
        uint2 p = st[i];
        int r = (int)(p.x >> 17);
        int pos = atomicAdd(&cur[r], 1);
        pairs[pos] = make_uint2(p.x & 0x1FFFFu, p.y);
    }
}

// ---- row gather: rowstart/rowend; readlane broadcast (proven R11) ----------
__global__ __launch_bounds__(256) void row_gather2_kernel(
    const __hip_bfloat16* __restrict__ hbf, const uint2* __restrict__ pairs,
    const int* __restrict__ rowstart, const int* __restrict__ rowend,
    float* __restrict__ out, int N)
{
    int row  = (int)((blockIdx.x * (size_t)blockDim.x + threadIdx.x) >> 6);
    int lane = threadIdx.x & 63;
    if (row >= N) return;

    int start = rowstart[row];
    int end   = rowend[row];

    const char* hb = reinterpret_cast<const char*>(hbf);
    const unsigned lbyte = (unsigned)lane << 2;
    float ax = 0.f, ay = 0.f;

    for (int e0 = start; e0 < end; e0 += 64) {
        int pl = e0 + lane;
        if (pl >= end) pl = end - 1;
        uint2 p = pairs[pl];
        int pc = (int)p.x, pv = (int)p.y;
        int m = end - e0; if (m > 64) m = 64;

        int idx = 0;
        const int m16 = m & ~15;
        for (; idx < m16; idx += 16) {
            unsigned c[16], vb[16], hv[16];
#pragma unroll
            for (int u = 0; u < 16; ++u) {
                c[u]  = (unsigned)__builtin_amdgcn_readlane(pc, idx + u);
                vb[u] = (unsigned)__builtin_amdgcn_readlane(pv, idx + u);
            }
#pragma unroll
            for (int u = 0; u < 16; ++u)
                hv[u] = *reinterpret_cast<const unsigned*>(hb + (((size_t)c[u]) << 8) + lbyte);
#pragma unroll
            for (int u = 0; u < 16; ++u) {
                float v = __uint_as_float(vb[u]);
                ax += v * __uint_as_float(hv[u] << 16);
                ay += v * __uint_as_float(hv[u] & 0xffff0000u);
            }
        }
        const int m8 = m & ~7;
        for (; idx < m8; idx += 8) {
            unsigned c[8], vb[8], hv[8];
#pragma unroll
            for (int u = 0; u < 8; ++u) {
                c[u]  = (unsigned)__builtin_amdgcn_readlane(pc, idx + u);
                vb[u] = (unsigned)__builtin_amdgcn_readlane(pv, idx + u);
            }
#pragma unroll
            for (int u = 0; u < 8; ++u)
                hv[u] = *reinterpret_cast<const unsigned*>(hb + (((size_t)c[u]) << 8) + lbyte);
#pragma unroll
            for (int u = 0; u < 8; ++u) {
                float v = __uint_as_float(vb[u]);
                ax += v * __uint_as_float(hv[u] << 16);
                ay += v * __uint_as_float(hv[u] & 0xffff0000u);
            }
        }
        for (; idx < m; ++idx) {
            unsigned c  = (unsigned)__builtin_amdgcn_readlane(pc, idx);
            unsigned vb = (unsigned)__builtin_amdgcn_readlane(pv, idx);
            unsigned hv = *reinterpret_cast<const unsigned*>(hb + (((size_t)c) << 8) + lbyte);
            float v = __uint_as_float(vb);
            ax += v * __uint_as_float(hv << 16);
            ay += v * __uint_as_float(hv & 0xffff0000u);
        }
    }

    f32x2 r2 = { ax, ay };
    __builtin_nontemporal_store(r2, reinterpret_cast<f32x2*>(out + (size_t)row * D) + lane);
}

// ---- fixup: apply overflow edges (normally zero) via atomics ---------------
__global__ __launch_bounds__(256) void fixup_kernel(
    const uint4* __restrict__ ovf, const int* __restrict__ ovfcnt,
    const __hip_bfloat16* __restrict__ hbf, float* __restrict__ out, int N)
{
    int cnt = *ovfcnt;
    if (cnt > OVFCAP) cnt = OVFCAP;
    const int wid  = threadIdx.x >> 6;
    const int lane = threadIdx.x & 63;
    const unsigned short* hb = reinterpret_cast<const unsigned short*>(hbf);
    for (int i = wid; i < cnt; i += 4) {
        uint4 e = ovf[i];
        if ((int)e.x >= N) continue;
        unsigned hv = *reinterpret_cast<const unsigned*>(hb + (size_t)e.y * D + lane * 2);
        float v = __uint_as_float(e.z);
        atomicAdd(out + (size_t)e.x * D + lane * 2,     v * __uint_as_float(hv << 16));
        atomicAdd(out + (size_t)e.x * D + lane * 2 + 1, v * __uint_as_float(hv & 0xffff0000u));
    }
}

// ============ R1 fallback ============

__global__ __launch_bounds__(256) void gemm_kernel(
    const float* __restrict__ x, const float* __restrict__ W,
    const float* __restrict__ bias, float* __restrict__ h, int N)
{
    __shared__ float sWt[D][D];
    __shared__ float sx[16][D];
    const int tid = threadIdx.x;
    for (int idx = tid; idx < D * D; idx += 256) {
        int o = idx >> 7, i = idx & (D - 1);
        sWt[i][o] = W[idx];
    }
    const int nbase = blockIdx.x * 16;
    for (int idx = tid; idx < 16 * D; idx += 256) {
        int r = idx >> 7, i = idx & (D - 1);
        int n = nbase + r;
        sx[r][i] = (n < N) ? x[(size_t)n * D + i] : 0.0f;
    }
    __syncthreads();
    const int c = tid & (D - 1);
    const int rg = tid >> 7;
    float acc[8];
#pragma unroll
    for (int k = 0; k < 8; ++k) acc[k] = 0.0f;
#pragma unroll 4
    for (int i = 0; i < D; ++i) {
        float w = sWt[i][c];
#pragma unroll
        for (int k = 0; k < 8; ++k) acc[k] += sx[rg * 8 + k][i] * w;
    }
    const float b = bias[c];
#pragma unroll
    for (int k = 0; k < 8; ++k) {
        int n = nbase + rg * 8 + k;
        if (n < N) h[(size_t)n * D + c] = acc[k] + b;
    }
}

__global__ __launch_bounds__(256) void scatter_kernel(
    const float* __restrict__ h, const float* __restrict__ vals,
    const int* __restrict__ rows, const int* __restrict__ cols,
    float* __restrict__ out, int E)
{
    const int wid  = (int)((blockIdx.x * (size_t)blockDim.x + threadIdx.x) >> 6);
    const int lane = threadIdx.x & 63;
    if (wid >= E) return;
    const int   r = rows[wid];
    const int   c = cols[wid];
    const float v = vals[wid];
    float2 hv = *reinterpret_cast<const float2*>(h + (size_t)c * D + lane * 2);
    atomicAdd(out + (size_t)r * D + lane * 2,     v * hv.x);
    atomicAdd(out + (size_t)r * D + lane * 2 + 1, v * hv.y);
}

// ---------------- launch ----------------
static inline size_t align16(size_t x) { return (x + 15) & ~(size_t)15; }

extern "C" void kernel_launch(void* const* d_in, const int* in_sizes, int n_in,
                              void* d_out, int out_size, void* d_ws, size_t ws_size,
                              hipStream_t stream)
{
    const float* x    = (const float*)d_in[0];
    const float* W    = (const float*)d_in[1];
    const float* bias = (const float*)d_in[2];
    const float* vals = (const float*)d_in[3];
    const int*   rows = (const int*)d_in[4];
    const int*   cols = (const int*)d_in[5];

    const int N = in_sizes[0] / D;
    const int E = in_sizes[3];
    float* out = (float*)d_out;

    const int NB = (N + RPB - 1) / RPB;
    const int GB = (N + 63) / 64;
    const int HB = (E + P1CHUNK - 1) / P1CHUNK;

    // ---- fast-path layout ----
    size_t f_wbf    = 0;
    size_t f_h      = f_wbf    + align16((size_t)D * D * 2);
    size_t f_pairs  = f_h      + align16((size_t)N * D * 2);
    size_t f_rs     = f_pairs  + align16((size_t)NB * CAP * 8);
    size_t f_re     = f_rs     + align16((size_t)N * 4);
    size_t f_bcount = f_re     + align16((size_t)N * 4);
    size_t f_ovf    = f_bcount + align16((size_t)(NB + 1) * 4);
    size_t need_fast = f_ovf   + align16((size_t)OVFCAP * 16);

    if (ws_size >= need_fast && NB <= NBMAX && N <= (1 << 17)) {
        char* ws = (char*)d_ws;
        unsigned short* wbf = (unsigned short*)(ws + f_wbf);
        __hip_bfloat16* hbf = (__hip_bfloat16*)(ws + f_h);
        uint2* pairs        = (uint2*)(ws + f_pairs);
        int*   rowstart     = (int*)(ws + f_rs);
        int*   rowend       = (int*)(ws + f_re);
        int*   bcount       = (int*)(ws + f_bcount);
        uint4* ovf          = (uint4*)(ws + f_ovf);

        hipMemsetAsync(bcount, 0, (size_t)(NB + 1) * 4, stream);

        wcvt_kernel<<<D * D / 8 / 256, 256, 0, stream>>>(W, wbf);

        gemm_pass1_kernel<<<GB + HB, 256, 0, stream>>>(
            x, wbf, bias, hbf, N, rows, cols, vals,
            bcount, pairs, ovf, NB, E, GB, HB);

        pass2_fixed_kernel<<<NB, 256, 0, stream>>>(pairs, bcount, rowstart, rowend, N);

        int gblocks = (int)(((size_t)N * 64 + 255) / 256);
        row_gather2_kernel<<<gblocks, 256, 0, stream>>>(hbf, pairs, rowstart, rowend, out, N);

        fixup_kernel<<<1, 256, 0, stream>>>(ovf, bcount + NB, hbf, out, N);
    } else {
        float* h = (float*)d_ws;
        hipMemsetAsync(out, 0, (size_t)out_size * sizeof(float), stream);
        gemm_kernel<<<(N + 15) / 16, 256, 0, stream>>>(x, W, bias, h, N);
        scatter_kernel<<<(E + 3) / 4, 256, 0, stream>>>(h, vals, rows, cols, out, E);
    }
}